// Round 1
// baseline (9370.061 us; speedup 1.0000x reference)
//
#include <hip/hip_runtime.h>
#include <hip/hip_bf16.h>

typedef __attribute__((ext_vector_type(8))) short short8;
typedef __attribute__((ext_vector_type(4))) float f32x4;

static constexpr int T = 512, B = 64, I = 512, H = 1024, O = 512;
static constexpr long TB = (long)T * B; // 32768

// ---------- bf16 helpers (RNE) ----------
__device__ __forceinline__ float bf2f(unsigned short h) {
  unsigned u = ((unsigned)h) << 16;
  return __builtin_bit_cast(float, u);
}
__device__ __forceinline__ unsigned short f2bf(float f) {
  unsigned u = __builtin_bit_cast(unsigned, f);
  u += 0x7fffu + ((u >> 16) & 1u);
  return (unsigned short)(u >> 16);
}

// ---------- workspace layout (bytes, all 256-aligned) ----------
static constexpr size_t WS_CNT    = 0;                         // 512 * 4 barrier counters
static constexpr size_t WS_SEQ    = 4096;                      // 32768*512 bf16
static constexpr size_t WS_WIH    = WS_SEQ + 33554432;         // 1024*512 bf16
static constexpr size_t WS_WHH    = WS_WIH + 1048576;          // 1024*1024 bf16
static constexpr size_t WS_WFC    = WS_WHH + 2097152;          // 512*1024 bf16
static constexpr size_t WS_XP     = WS_WFC + 1048576;          // 32768*1024 bf16
static constexpr size_t WS_HS     = WS_XP + 67108864;          // 32768*1024 bf16
// total = WS_HS + 67108864 ≈ 164 MB

// ---------- prep: fp32 -> bf16 ----------
__global__ void prep_kernel(const float* __restrict__ seq, const float* __restrict__ wih,
                            const float* __restrict__ whh, const float* __restrict__ wfc,
                            unsigned short* __restrict__ seq_bf, unsigned short* __restrict__ wih_bf,
                            unsigned short* __restrict__ whh_bf, unsigned short* __restrict__ wfc_bf) {
  long i = (long)blockIdx.x * blockDim.x + threadIdx.x;
  const long S0 = TB * I, S1 = (long)H * I, S2 = (long)H * H, S3 = (long)O * H;
  if (i < S0) seq_bf[i] = f2bf(seq[i]);
  else if (i < S0 + S1) wih_bf[i - S0] = f2bf(wih[i - S0]);
  else if (i < S0 + S1 + S2) whh_bf[i - S0 - S1] = f2bf(whh[i - S0 - S1]);
  else if (i < S0 + S1 + S2 + S3) wfc_bf[i - S0 - S1 - S2] = f2bf(wfc[i - S0 - S1 - S2]);
}

// ---------- bulk GEMM: C[m,n] = sum_k A[m,k]*B[n,k] + bias0[n] (+ bias1[n]) ----------
// A: [M,K] bf16 K-contig.  B: [N,K] bf16 K-contig.  128x128 tile, BK=32, 256 threads.
__global__ __launch_bounds__(256) void gemm_bt(const unsigned short* __restrict__ A,
                                               const unsigned short* __restrict__ Bm,
                                               int M, int N, int K,
                                               const float* __restrict__ bias0,
                                               const float* __restrict__ bias1,
                                               float* __restrict__ Cf,
                                               unsigned short* __restrict__ Cb) {
  __shared__ __align__(16) unsigned short lA[128][40]; // 32 k + 8 pad
  __shared__ __align__(16) unsigned short lB[128][40];
  const int tid = threadIdx.x;
  const int wave = tid >> 6, lane = tid & 63;
  const int wm = (wave >> 1) * 64, wn = (wave & 1) * 64;
  const int lr = lane & 15, lq = lane >> 4;
  const long m0 = (long)blockIdx.y * 128, n0 = (long)blockIdx.x * 128;

  f32x4 acc[4][4];
#pragma unroll
  for (int i = 0; i < 4; ++i)
#pragma unroll
    for (int j = 0; j < 4; ++j) acc[i][j] = (f32x4){0.f, 0.f, 0.f, 0.f};

  const int srow = tid >> 2;            // 0..63
  const int scol = (tid & 3) * 8;       // 0,8,16,24
  const unsigned short* Ag = A + (m0 + srow) * K + scol;
  const unsigned short* Bg = Bm + (n0 + srow) * K + scol;

  for (int k0 = 0; k0 < K; k0 += 32) {
    __syncthreads();
    *(short8*)&lA[srow][scol]      = *(const short8*)(Ag + k0);
    *(short8*)&lA[srow + 64][scol] = *(const short8*)(Ag + 64L * K + k0);
    *(short8*)&lB[srow][scol]      = *(const short8*)(Bg + k0);
    *(short8*)&lB[srow + 64][scol] = *(const short8*)(Bg + 64L * K + k0);
    __syncthreads();
    short8 af[4], bf[4];
#pragma unroll
    for (int i = 0; i < 4; ++i) af[i] = *(const short8*)&lA[wm + i * 16 + lr][lq * 8];
#pragma unroll
    for (int j = 0; j < 4; ++j) bf[j] = *(const short8*)&lB[wn + j * 16 + lr][lq * 8];
#pragma unroll
    for (int i = 0; i < 4; ++i)
#pragma unroll
      for (int j = 0; j < 4; ++j)
        acc[i][j] = __builtin_amdgcn_mfma_f32_16x16x32_bf16(af[i], bf[j], acc[i][j], 0, 0, 0);
  }

  // epilogue: C row = (lane>>4)*4 + reg, col = lane&15  [verified m89/m91]
#pragma unroll
  for (int j = 0; j < 4; ++j) {
    const long n = n0 + wn + j * 16 + lr;
    float bv = bias0[n] + (bias1 ? bias1[n] : 0.f);
#pragma unroll
    for (int i = 0; i < 4; ++i) {
#pragma unroll
      for (int r = 0; r < 4; ++r) {
        const long m = m0 + wm + i * 16 + lq * 4 + r;
        const float v = acc[i][j][r] + bv;
        if (Cb) Cb[m * N + n] = f2bf(v);
        else    Cf[m * N + n] = v;
      }
    }
  }
}

// ---------- recurrence: persistent, 64 WGs x 256 thr, W_hh slice in VGPRs ----------
__global__ __launch_bounds__(256, 1) void rnn_scan(const unsigned short* __restrict__ xp,
                                                   const unsigned short* __restrict__ whh,
                                                   unsigned short* __restrict__ hs,
                                                   unsigned int* __restrict__ cnt) {
  const int wave = threadIdx.x >> 6, lane = threadIdx.x & 63;
  const int n0 = blockIdx.x * 16;   // this WG's 16 hidden columns
  const int m0 = wave * 16;         // this wave's 16 batch rows
  const int lr = lane & 15, lq = lane >> 4;
  const int NWG = 64;

  // preload W_hh fragments: B[k][n] = whh[n0+lr][k], k = ks*32 + lq*8 + i
  short8 bfrag[32];
  {
    const unsigned short* wrow = whh + (long)(n0 + lr) * H + lq * 8;
#pragma unroll
    for (int ks = 0; ks < 32; ++ks) bfrag[ks] = *(const short8*)(wrow + ks * 32);
  }

  for (int t = 0; t < T; ++t) {
    f32x4 acc0 = (f32x4){0.f, 0.f, 0.f, 0.f};
    f32x4 acc1 = (f32x4){0.f, 0.f, 0.f, 0.f};
    if (t > 0) {
      const unsigned short* hrow = hs + (long)(t - 1) * (B * H) + (long)(m0 + lr) * H + lq * 8;
      short8 af[32];
#pragma unroll
      for (int ks = 0; ks < 32; ++ks) af[ks] = *(const short8*)(hrow + ks * 32);
#pragma unroll
      for (int ks = 0; ks < 32; ks += 2) {
        acc0 = __builtin_amdgcn_mfma_f32_16x16x32_bf16(af[ks],     bfrag[ks],     acc0, 0, 0, 0);
        acc1 = __builtin_amdgcn_mfma_f32_16x16x32_bf16(af[ks + 1], bfrag[ks + 1], acc1, 0, 0, 0);
      }
    }
    // epilogue: row=(lane>>4)*4+r (batch), col=lane&15 (hidden)
#pragma unroll
    for (int r = 0; r < 4; ++r) {
      const int b = m0 + lq * 4 + r;
      const long idx = (long)t * (B * H) + (long)b * H + n0 + lr;
      const float pre = acc0[r] + acc1[r] + bf2f(xp[idx]);
      hs[idx] = f2bf(tanhf(pre));
    }
    if (t < T - 1) {
      __threadfence();        // release my stores to device scope
      __syncthreads();
      if (threadIdx.x == 0) {
        __hip_atomic_fetch_add(&cnt[t], 1u, __ATOMIC_RELEASE, __HIP_MEMORY_SCOPE_AGENT);
        while (__hip_atomic_load(&cnt[t], __ATOMIC_ACQUIRE, __HIP_MEMORY_SCOPE_AGENT) < (unsigned)NWG)
          __builtin_amdgcn_s_sleep(2);
      }
      __syncthreads();
      __threadfence();        // acquire side: invalidate before reading fresh h
    }
  }
}

extern "C" void kernel_launch(void* const* d_in, const int* in_sizes, int n_in,
                              void* d_out, int out_size, void* d_ws, size_t ws_size,
                              hipStream_t stream) {
  const float* seq  = (const float*)d_in[0];
  const float* Wih  = (const float*)d_in[1];
  const float* Whh  = (const float*)d_in[2];
  const float* b_ih = (const float*)d_in[3];
  const float* b_hh = (const float*)d_in[4];
  const float* Wfc  = (const float*)d_in[5];
  const float* b_fc = (const float*)d_in[6];
  float* out = (float*)d_out;

  char* ws = (char*)d_ws;
  unsigned int*  cnt    = (unsigned int*)(ws + WS_CNT);
  unsigned short* seq_bf = (unsigned short*)(ws + WS_SEQ);
  unsigned short* wih_bf = (unsigned short*)(ws + WS_WIH);
  unsigned short* whh_bf = (unsigned short*)(ws + WS_WHH);
  unsigned short* wfc_bf = (unsigned short*)(ws + WS_WFC);
  unsigned short* xp_bf  = (unsigned short*)(ws + WS_XP);
  unsigned short* hs_bf  = (unsigned short*)(ws + WS_HS);

  // zero barrier counters (re-poisoned to 0xAA before every timed launch)
  hipMemsetAsync(cnt, 0, 4096, stream);

  // 1) bf16 conversions
  {
    const long total = TB * I + (long)H * I + (long)H * H + (long)O * H;
    const int blocks = (int)((total + 255) / 256);
    prep_kernel<<<blocks, 256, 0, stream>>>(seq, Wih, Whh, Wfc, seq_bf, wih_bf, whh_bf, wfc_bf);
  }

  // 2) x_proj = seq @ W_ih^T + b_ih + b_hh   -> xp_bf [32768,1024]
  {
    dim3 grid(H / 128, TB / 128);
    gemm_bt<<<grid, 256, 0, stream>>>(seq_bf, wih_bf, (int)TB, H, I, b_ih, b_hh, nullptr, xp_bf);
  }

  // 3) recurrence -> hs_bf [32768,1024]
  rnn_scan<<<64, 256, 0, stream>>>(xp_bf, whh_bf, hs_bf, cnt);

  // 4) out = hs @ W_fc^T + b_fc  -> d_out fp32 [32768,512]
  {
    dim3 grid(O / 128, TB / 128);
    gemm_bt<<<grid, 256, 0, stream>>>(hs_bf, wfc_bf, (int)TB, O, H, b_fc, nullptr, out, nullptr);
  }
}

// Round 2
// 2017.413 us; speedup vs baseline: 4.6446x; 4.6446x over previous
//
#include <hip/hip_runtime.h>
#include <hip/hip_bf16.h>

typedef __attribute__((ext_vector_type(8))) short short8;
typedef __attribute__((ext_vector_type(4))) float f32x4;
typedef __attribute__((ext_vector_type(4))) unsigned int u32x4;

static constexpr int T = 512, B = 64, I = 512, H = 1024, O = 512;
static constexpr long TB = (long)T * B; // 32768

// ---------- bf16 helpers (RNE) ----------
__device__ __forceinline__ float bf2f(unsigned short h) {
  unsigned u = ((unsigned)h) << 16;
  return __builtin_bit_cast(float, u);
}
__device__ __forceinline__ unsigned short f2bf(float f) {
  unsigned u = __builtin_bit_cast(unsigned, f);
  u += 0x7fffu + ((u >> 16) & 1u);
  return (unsigned short)(u >> 16);
}

// ---------- agent-coherent (MALL-direct) memory ops: bypass L1+L2 ----------
__device__ __forceinline__ u32x4 load_sc(const void* p) {
  u32x4 v;
  asm volatile("global_load_dwordx4 %0, %1, off sc0 sc1" : "=v"(v) : "v"(p));
  return v;
}
__device__ __forceinline__ void store_sc_u16(void* p, unsigned int v) {
  asm volatile("global_store_short %0, %1, off sc0 sc1" : : "v"(p), "v"(v) : "memory");
}
__device__ __forceinline__ void waitcnt_vm0() {
  asm volatile("s_waitcnt vmcnt(0)" ::: "memory");
}

// ---------- workspace layout (bytes) ----------
static constexpr size_t WS_CNT = 0;                     // 4 groups * 512 counters * 4B = 8KB
static constexpr size_t WS_SEQ = 8192;                  // 32768*512 bf16
static constexpr size_t WS_WIH = WS_SEQ + 33554432;     // 1024*512 bf16
static constexpr size_t WS_WHH = WS_WIH + 1048576;      // 1024*1024 bf16
static constexpr size_t WS_WFC = WS_WHH + 2097152;      // 512*1024 bf16
static constexpr size_t WS_XP  = WS_WFC + 1048576;      // 32768*1024 bf16
static constexpr size_t WS_HS  = WS_XP + 67108864;      // 32768*1024 bf16

// ---------- prep: fp32 -> bf16 ----------
__global__ void prep_kernel(const float* __restrict__ seq, const float* __restrict__ wih,
                            const float* __restrict__ whh, const float* __restrict__ wfc,
                            unsigned short* __restrict__ seq_bf, unsigned short* __restrict__ wih_bf,
                            unsigned short* __restrict__ whh_bf, unsigned short* __restrict__ wfc_bf) {
  long i = (long)blockIdx.x * blockDim.x + threadIdx.x;
  const long S0 = TB * I, S1 = (long)H * I, S2 = (long)H * H, S3 = (long)O * H;
  if (i < S0) seq_bf[i] = f2bf(seq[i]);
  else if (i < S0 + S1) wih_bf[i - S0] = f2bf(wih[i - S0]);
  else if (i < S0 + S1 + S2) whh_bf[i - S0 - S1] = f2bf(whh[i - S0 - S1]);
  else if (i < S0 + S1 + S2 + S3) wfc_bf[i - S0 - S1 - S2] = f2bf(wfc[i - S0 - S1 - S2]);
}

// ---------- bulk GEMM: C[m,n] = sum_k A[m,k]*B[n,k] + bias0[n] (+ bias1[n]) ----------
__global__ __launch_bounds__(256) void gemm_bt(const unsigned short* __restrict__ A,
                                               const unsigned short* __restrict__ Bm,
                                               int M, int N, int K,
                                               const float* __restrict__ bias0,
                                               const float* __restrict__ bias1,
                                               float* __restrict__ Cf,
                                               unsigned short* __restrict__ Cb) {
  __shared__ __align__(16) unsigned short lA[128][40];
  __shared__ __align__(16) unsigned short lB[128][40];
  const int tid = threadIdx.x;
  const int wave = tid >> 6, lane = tid & 63;
  const int wm = (wave >> 1) * 64, wn = (wave & 1) * 64;
  const int lr = lane & 15, lq = lane >> 4;
  const long m0 = (long)blockIdx.y * 128, n0 = (long)blockIdx.x * 128;

  f32x4 acc[4][4];
#pragma unroll
  for (int i = 0; i < 4; ++i)
#pragma unroll
    for (int j = 0; j < 4; ++j) acc[i][j] = (f32x4){0.f, 0.f, 0.f, 0.f};

  const int srow = tid >> 2;
  const int scol = (tid & 3) * 8;
  const unsigned short* Ag = A + (m0 + srow) * K + scol;
  const unsigned short* Bg = Bm + (n0 + srow) * K + scol;

  for (int k0 = 0; k0 < K; k0 += 32) {
    __syncthreads();
    *(short8*)&lA[srow][scol]      = *(const short8*)(Ag + k0);
    *(short8*)&lA[srow + 64][scol] = *(const short8*)(Ag + 64L * K + k0);
    *(short8*)&lB[srow][scol]      = *(const short8*)(Bg + k0);
    *(short8*)&lB[srow + 64][scol] = *(const short8*)(Bg + 64L * K + k0);
    __syncthreads();
    short8 af[4], bf[4];
#pragma unroll
    for (int i = 0; i < 4; ++i) af[i] = *(const short8*)&lA[wm + i * 16 + lr][lq * 8];
#pragma unroll
    for (int j = 0; j < 4; ++j) bf[j] = *(const short8*)&lB[wn + j * 16 + lr][lq * 8];
#pragma unroll
    for (int i = 0; i < 4; ++i)
#pragma unroll
      for (int j = 0; j < 4; ++j)
        acc[i][j] = __builtin_amdgcn_mfma_f32_16x16x32_bf16(af[i], bf[j], acc[i][j], 0, 0, 0);
  }

#pragma unroll
  for (int j = 0; j < 4; ++j) {
    const long n = n0 + wn + j * 16 + lr;
    float bv = bias0[n] + (bias1 ? bias1[n] : 0.f);
#pragma unroll
    for (int i = 0; i < 4; ++i) {
#pragma unroll
      for (int r = 0; r < 4; ++r) {
        const long m = m0 + wm + i * 16 + lq * 4 + r;
        const float v = acc[i][j][r] + bv;
        if (Cb) Cb[m * N + n] = f2bf(v);
        else    Cf[m * N + n] = v;
      }
    }
  }
}

// ---------- recurrence v2: 4 independent batch groups x 16 N-slice WGs ----------
// WG (256 thr, 4 waves): group g = blk>>4 owns batches [g*16, g*16+16);
// slice s = blk&15, wave w owns cols [s*64 + w*16, +16). W_hh slice in VGPRs.
// h exchange via MALL-direct sc0sc1 ops; per-(group,step) arrival counters.
__global__ __launch_bounds__(256, 1) void rnn_scan2(const unsigned short* __restrict__ xp,
                                                    const unsigned short* __restrict__ whh,
                                                    unsigned short* __restrict__ hs,
                                                    unsigned int* __restrict__ cnt) {
  const int tid = threadIdx.x;
  const int wave = tid >> 6, lane = tid & 63;
  const int lr = lane & 15, lq = lane >> 4;
  const int g = blockIdx.x >> 4;
  const int s = blockIdx.x & 15;
  const int n0 = s * 64 + wave * 16;
  const int b0 = g * 16;
  unsigned int* gcnt = cnt + g * T;

  // 16 rows x 1024 cols, +8 pad keeps rows 16B-aligned and spreads bank groups
  __shared__ __align__(16) unsigned short hsh[16][1032];

  // preload W_hh fragments: B[k][n] with n = n0+lr, k = ks*32 + lq*8 + j
  short8 bfrag[32];
  {
    const unsigned short* wrow = whh + (long)(n0 + lr) * H + lq * 8;
#pragma unroll
    for (int ks = 0; ks < 32; ++ks) bfrag[ks] = *(const short8*)(wrow + ks * 32);
  }

  const int srow = tid >> 4;       // staging: row 0..15
  const int scb  = tid & 15;       // staging: 16B chunk

  for (int t = 0; t < T; ++t) {
    // xp prefetch — independent of the barrier, overlaps the poll
    float xpv[4];
#pragma unroll
    for (int r = 0; r < 4; ++r)
      xpv[r] = bf2f(xp[(long)t * (B * H) + (long)(b0 + lq * 4 + r) * H + n0 + lr]);

    float hv[4] = {0.f, 0.f, 0.f, 0.f};
    if (t > 0) {
      if (tid == 0) {
        while (__hip_atomic_load(&gcnt[t - 1], __ATOMIC_RELAXED, __HIP_MEMORY_SCOPE_AGENT) < 16u)
          __builtin_amdgcn_s_sleep(1);
      }
      __syncthreads();
      // stage h_{t-1}[b0..b0+16, :] (32KB) into LDS via MALL-direct loads
      {
        const unsigned short* src = hs + (long)(t - 1) * (B * H) + (long)(b0 + srow) * H;
        u32x4 tmp[8];
#pragma unroll
        for (int j = 0; j < 8; ++j)
          tmp[j] = load_sc(src + scb * 8 + j * 128);
        waitcnt_vm0();
#pragma unroll
        for (int j = 0; j < 8; ++j)
          *(u32x4*)&hsh[srow][scb * 8 + j * 128] = tmp[j];
      }
      __syncthreads();
      // MFMA over K=1024: 32 mfma as 4 interleaved chains
      f32x4 a0 = (f32x4){0.f,0.f,0.f,0.f}, a1 = a0, a2 = a0, a3 = a0;
#pragma unroll
      for (int ks = 0; ks < 32; ks += 4) {
        short8 f0 = *(const short8*)&hsh[lr][(ks + 0) * 32 + lq * 8];
        short8 f1 = *(const short8*)&hsh[lr][(ks + 1) * 32 + lq * 8];
        short8 f2 = *(const short8*)&hsh[lr][(ks + 2) * 32 + lq * 8];
        short8 f3 = *(const short8*)&hsh[lr][(ks + 3) * 32 + lq * 8];
        a0 = __builtin_amdgcn_mfma_f32_16x16x32_bf16(f0, bfrag[ks + 0], a0, 0, 0, 0);
        a1 = __builtin_amdgcn_mfma_f32_16x16x32_bf16(f1, bfrag[ks + 1], a1, 0, 0, 0);
        a2 = __builtin_amdgcn_mfma_f32_16x16x32_bf16(f2, bfrag[ks + 2], a2, 0, 0, 0);
        a3 = __builtin_amdgcn_mfma_f32_16x16x32_bf16(f3, bfrag[ks + 3], a3, 0, 0, 0);
      }
#pragma unroll
      for (int r = 0; r < 4; ++r) hv[r] = (a0[r] + a1[r]) + (a2[r] + a3[r]);
    }
    // h_t = tanh(W.h_{t-1} + xp); store MALL-direct (doubles as final hs output)
#pragma unroll
    for (int r = 0; r < 4; ++r) {
      const float v = tanhf(hv[r] + xpv[r]);
      store_sc_u16(hs + (long)t * (B * H) + (long)(b0 + lq * 4 + r) * H + n0 + lr,
                   (unsigned int)f2bf(v));
    }
    if (t < T - 1) {
      waitcnt_vm0();        // my h stores are at MALL
      __syncthreads();      // all 4 waves drained
      if (tid == 0)
        __hip_atomic_fetch_add(&gcnt[t], 1u, __ATOMIC_RELAXED, __HIP_MEMORY_SCOPE_AGENT);
    }
  }
}

extern "C" void kernel_launch(void* const* d_in, const int* in_sizes, int n_in,
                              void* d_out, int out_size, void* d_ws, size_t ws_size,
                              hipStream_t stream) {
  const float* seq  = (const float*)d_in[0];
  const float* Wih  = (const float*)d_in[1];
  const float* Whh  = (const float*)d_in[2];
  const float* b_ih = (const float*)d_in[3];
  const float* b_hh = (const float*)d_in[4];
  const float* Wfc  = (const float*)d_in[5];
  const float* b_fc = (const float*)d_in[6];
  float* out = (float*)d_out;

  char* ws = (char*)d_ws;
  unsigned int*   cnt    = (unsigned int*)(ws + WS_CNT);
  unsigned short* seq_bf = (unsigned short*)(ws + WS_SEQ);
  unsigned short* wih_bf = (unsigned short*)(ws + WS_WIH);
  unsigned short* whh_bf = (unsigned short*)(ws + WS_WHH);
  unsigned short* wfc_bf = (unsigned short*)(ws + WS_WFC);
  unsigned short* xp_bf  = (unsigned short*)(ws + WS_XP);
  unsigned short* hs_bf  = (unsigned short*)(ws + WS_HS);

  hipMemsetAsync(cnt, 0, 8192, stream);

  {
    const long total = TB * I + (long)H * I + (long)H * H + (long)O * H;
    const int blocks = (int)((total + 255) / 256);
    prep_kernel<<<blocks, 256, 0, stream>>>(seq, Wih, Whh, Wfc, seq_bf, wih_bf, whh_bf, wfc_bf);
  }

  {
    dim3 grid(H / 128, TB / 128);
    gemm_bt<<<grid, 256, 0, stream>>>(seq_bf, wih_bf, (int)TB, H, I, b_ih, b_hh, nullptr, xp_bf);
  }

  rnn_scan2<<<64, 256, 0, stream>>>(xp_bf, whh_bf, hs_bf, cnt);

  {
    dim3 grid(O / 128, TB / 128);
    gemm_bt<<<grid, 256, 0, stream>>>(hs_bf, wfc_bf, (int)TB, O, H, b_fc, nullptr, out, nullptr);
  }
}